// Round 7
// baseline (447.899 us; speedup 1.0000x reference)
//
#include <hip/hip_runtime.h>
#include <math.h>

#define DF 768      // feature dim
#define NN 64       // nodes
#define DN 832      // batch row stride (D + N)
#define HB 49152    // halves per batch item in h buffers (768*64)
#define NEG_SLOPE 0.2f

typedef _Float16 f16;
typedef __attribute__((ext_vector_type(4))) _Float16 f16x4;
typedef __attribute__((ext_vector_type(8))) _Float16 f16x8;
typedef __attribute__((ext_vector_type(4))) float f32x4;

__device__ __forceinline__ float tanh_fast(float x) {
  return 1.0f - 2.0f / (__expf(2.0f * x) + 1.0f);
}

// ---------- prep: transpose w (768x768 fp32) -> wT[o][k] f16 ----------
__global__ void prep_wT(const float* __restrict__ w, f16* __restrict__ wT) {
  __shared__ float tile[32][33];
  int bx = blockIdx.x % 24;
  int by = blockIdx.x / 24;
  int tx = threadIdx.x & 31;
  int ty = threadIdx.x >> 5;
#pragma unroll
  for (int rr = 0; rr < 4; ++rr)
    tile[ty + rr * 8][tx] = w[(size_t)(by * 32 + ty + rr * 8) * DF + bx * 32 + tx];
  __syncthreads();
#pragma unroll
  for (int rr = 0; rr < 4; ++rr)
    wT[(size_t)(bx * 32 + ty + rr * 8) * DF + by * 32 + tx] = (f16)tile[tx][ty + rr * 8];
}

// ---------- prep: mlp_w fp32 -> f16 ----------
__global__ void prep_mlp(const float* __restrict__ mw, f16* __restrict__ mwh) {
  int i = blockIdx.x * 256 + threadIdx.x;
  mwh[i] = (f16)mw[i];
}

// ---------- hp = h @ w : M=32768, N=768, K=768, double-buffered ----------
// R6: single-buffered staging exposed full global latency at every barrier
// (115 us, MfmaUtil 13%, 1.8 TB/s effective). R7: reg-prefetch dbuf, one
// barrier/iter; grid bn-fastest so adjacent blocks share the A-stripe.
__global__ __launch_bounds__(256, 2) void gemm_hp(
    const float* __restrict__ batch,
    const f16* __restrict__ hIn,
    const f16* __restrict__ wT,
    f16* __restrict__ hpT,
    int is_l1)
{
  __shared__ __align__(16) f16 At[2][128 * 72];   // 2 x 18432 B
  __shared__ __align__(16) f16 Bt[2][128 * 72];
  const int tid  = threadIdx.x;
  const int lane = tid & 63;
  const int wv   = tid >> 6;     // 0..3
  const int l16  = lane & 15;
  const int quad = lane >> 4;
  const int bn   = blockIdx.x % 6;    // N tile (fastest -> A-stripe reuse)
  const int bm   = blockIdx.x / 6;    // M tile
  const int m0w  = (wv & 1) * 64;
  const int n0w  = (wv >> 1) * 64;

  // staging thread mapping
  const int rA1 = tid >> 4, cA1 = (tid & 15) * 4;  // layer1: float4
  const int rH  = tid >> 3, cH  = (tid & 7) * 8;   // layer2 A / B: f16x8

  f32x4 acc[4][4];
#pragma unroll
  for (int rt = 0; rt < 4; ++rt)
#pragma unroll
    for (int ct = 0; ct < 4; ++ct)
      acc[rt][ct] = (f32x4){0.f, 0.f, 0.f, 0.f};

  float4 aRf[8];
  f16x8  aRh[4];
  f16x8  bR[4];

#define PREF(KT_) do {                                                          \
    const int k0_ = (KT_) * 64;                                                 \
    if (is_l1) {                                                                \
      _Pragma("unroll")                                                         \
      for (int p = 0; p < 8; ++p) {                                             \
        int gm = bm * 128 + p * 16 + rA1;                                       \
        aRf[p] = *(const float4*)&batch[(size_t)(gm >> 6) * (NN * DN) +         \
                                        (size_t)(gm & 63) * DN + k0_ + cA1];    \
      }                                                                         \
    } else {                                                                    \
      _Pragma("unroll")                                                         \
      for (int p = 0; p < 4; ++p) {                                             \
        int gm = bm * 128 + p * 32 + rH;                                        \
        aRh[p] = *(const f16x8*)&hIn[(size_t)gm * DF + k0_ + cH];               \
      }                                                                         \
    }                                                                           \
    _Pragma("unroll")                                                           \
    for (int p = 0; p < 4; ++p)                                                 \
      bR[p] = *(const f16x8*)&wT[(size_t)(bn * 128 + p * 32 + rH) * DF + k0_ + cH]; \
  } while (0)

#define WRITE(BUF_) do {                                                        \
    if (is_l1) {                                                                \
      _Pragma("unroll")                                                         \
      for (int p = 0; p < 8; ++p)                                               \
        *(f16x4*)&At[BUF_][(p * 16 + rA1) * 72 + cA1] =                         \
            (f16x4){(f16)aRf[p].x, (f16)aRf[p].y, (f16)aRf[p].z, (f16)aRf[p].w};\
    } else {                                                                    \
      _Pragma("unroll")                                                         \
      for (int p = 0; p < 4; ++p)                                               \
        *(f16x8*)&At[BUF_][(p * 32 + rH) * 72 + cH] = aRh[p];                   \
    }                                                                           \
    _Pragma("unroll")                                                           \
    for (int p = 0; p < 4; ++p)                                                 \
      *(f16x8*)&Bt[BUF_][(p * 32 + rH) * 72 + cH] = bR[p];                      \
  } while (0)

  PREF(0);
  WRITE(0);
  __syncthreads();

  for (int kt = 0; kt < 12; ++kt) {
    const int cur = kt & 1;
    if (kt < 11) PREF(kt + 1);
#pragma unroll
    for (int ks = 0; ks < 2; ++ks) {
      f16x8 af[4], bf[4];
#pragma unroll
      for (int rt = 0; rt < 4; ++rt)
        af[rt] = *(const f16x8*)&At[cur][(m0w + rt * 16 + l16) * 72 + ks * 32 + quad * 8];
#pragma unroll
      for (int ct = 0; ct < 4; ++ct)
        bf[ct] = *(const f16x8*)&Bt[cur][(n0w + ct * 16 + l16) * 72 + ks * 32 + quad * 8];
#pragma unroll
      for (int rt = 0; rt < 4; ++rt)
#pragma unroll
        for (int ct = 0; ct < 4; ++ct)
          acc[rt][ct] = __builtin_amdgcn_mfma_f32_16x16x32_f16(af[rt], bf[ct], acc[rt][ct], 0, 0, 0);
    }
    if (kt < 11) {
      WRITE(cur ^ 1);
      __syncthreads();
    }
  }
#undef PREF
#undef WRITE

  // epilogue: hpT[b][o][m], 4 consecutive m per frag -> f16x4 store
#pragma unroll
  for (int rt = 0; rt < 4; ++rt)
#pragma unroll
    for (int ct = 0; ct < 4; ++ct) {
      int gm = bm * 128 + m0w + rt * 16 + quad * 4;
      int b = gm >> 6, mm = gm & 63;
      int o = bn * 128 + n0w + ct * 16 + l16;
      f16x4 hv = {(f16)acc[rt][ct][0], (f16)acc[rt][ct][1],
                  (f16)acc[rt][ct][2], (f16)acc[rt][ct][3]};
      *(f16x4*)&hpT[(size_t)b * HB + (size_t)o * 64 + mm] = hv;
    }
}

// ---------- attention layer 1: tanh-dots + masked softmax + h1 = attn@hp + bias ----------
// R7: no big LDS hp stage (R6's 98 KB forced 1 WG/CU + giant barriers).
// hp read straight from L2/L3 in both passes. 256 thr, ~21 KB LDS.
__global__ __launch_bounds__(256) void attn_l1(
    const float* __restrict__ batch,
    const f16* __restrict__ hpT,      // [b][o][m]
    const float* __restrict__ a_src,
    const float* __restrict__ a_dst,
    const float* __restrict__ gat_bias,
    f16* __restrict__ h1)             // [b][m][o]
{
  __shared__ __align__(16) f16 attnL[NN * 72];
  __shared__ float asrcL[DF], adstL[DF], biasL[DF];
  __shared__ float redS[4 * NN], redD[4 * NN];
  __shared__ float srcv[NN], dstv[NN];
  __shared__ unsigned long long maskRow[NN];

  const int tid  = threadIdx.x;
  const int lane = tid & 63;
  const int wv   = tid >> 6;    // 0..3
  const int l16  = lane & 15;
  const int quad = lane >> 4;
  const int b    = blockIdx.x;
  const float* bb = batch + (size_t)b * (NN * DN);
  const f16* hp = hpT + (size_t)b * HB;

  for (int i = tid; i < DF; i += 256) {
    asrcL[i] = a_src[i];
    adstL[i] = a_dst[i];
    biasL[i] = gat_bias[i];
  }
  // adjacency: wave wv rows 16wv..+15
#pragma unroll
  for (int r = 0; r < 16; ++r) {
    int n = wv * 16 + r;
    float av = bb[n * DN + DF + lane];
    unsigned long long m = __ballot(av != 0.0f);
    if (lane == 0) maskRow[n] = m | (1ULL << n);
  }
  __syncthreads();

  // tanh dots: wave wv covers o in [192wv, +192), lane = m (global, L2/L3-hot)
  {
    float s = 0.f, d = 0.f;
    int o0 = wv * 192;
    for (int oi = 0; oi < 192; ++oi) {
      int o = o0 + oi;
      float t = tanh_fast((float)hp[(size_t)o * 64 + lane]);
      s += t * asrcL[o];
      d += t * adstL[o];
    }
    redS[wv * 64 + lane] = s;
    redD[wv * 64 + lane] = d;
  }
  __syncthreads();
  if (tid < 64) {
    srcv[tid] = redS[tid] + redS[64 + tid] + redS[128 + tid] + redS[192 + tid];
    dstv[tid] = redD[tid] + redD[64 + tid] + redD[128 + tid] + redD[192 + tid];
  }
  __syncthreads();

  // softmax: wave wv rows 16wv..+15, lane = neighbor m
#pragma unroll
  for (int r = 0; r < 16; ++r) {
    int n = wv * 16 + r;
    float logit = srcv[n] + dstv[lane];
    logit = logit >= 0.f ? logit : NEG_SLOPE * logit;
    bool ok = (maskRow[n] >> lane) & 1ULL;
    float v = ok ? logit : -1e30f;
    float mx = v;
#pragma unroll
    for (int off = 32; off > 0; off >>= 1) mx = fmaxf(mx, __shfl_xor(mx, off, 64));
    float e = ok ? __expf(v - mx) : 0.f;
    float sm = e;
#pragma unroll
    for (int off = 32; off > 0; off >>= 1) sm += __shfl_xor(sm, off, 64);
    attnL[n * 72 + lane] = (f16)(e / sm);
  }
  __syncthreads();

  // GEMM2: wave wv outputs cols o in [192wv, +192) as 12 tiles of 16;
  // B-fragments are 16-B global loads from hp (L2-hot).
  for (int ct = 0; ct < 12; ++ct) {
    int c0 = wv * 192 + ct * 16;
    f32x4 a4[4];
#pragma unroll
    for (int rt = 0; rt < 4; ++rt) a4[rt] = (f32x4){0.f, 0.f, 0.f, 0.f};
#pragma unroll
    for (int ks = 0; ks < 2; ++ks) {
      f16x8 bf = *(const f16x8*)&hp[(size_t)(c0 + l16) * 64 + ks * 32 + quad * 8];
#pragma unroll
      for (int rt = 0; rt < 4; ++rt) {
        f16x8 af = *(const f16x8*)&attnL[(rt * 16 + l16) * 72 + ks * 32 + quad * 8];
        a4[rt] = __builtin_amdgcn_mfma_f32_16x16x32_f16(af, bf, a4[rt], 0, 0, 0);
      }
    }
    float bv = biasL[c0 + l16];
#pragma unroll
    for (int rt = 0; rt < 4; ++rt)
#pragma unroll
      for (int i = 0; i < 4; ++i) {
        int n = rt * 16 + quad * 4 + i;
        h1[(size_t)b * HB + (size_t)n * DF + c0 + l16] = (f16)(a4[rt][i] + bv);
      }
  }
}

// ---------- attention layer 2: only row 0 -> cneigh (l2-normed) ----------
__global__ __launch_bounds__(256) void attn_l2(
    const float* __restrict__ batch,
    const f16* __restrict__ hpT,
    const float* __restrict__ a_src,
    const float* __restrict__ a_dst,
    const float* __restrict__ gat_bias,
    f16* __restrict__ cneighW)
{
  __shared__ float asrcL[DF], adstL[DF], biasL[DF];
  __shared__ float redS[4 * NN], redD[4 * NN];
  __shared__ float dstv[NN], attn0[NN], h2row[DF], ssq[4];
  __shared__ float srcv0;
  __shared__ unsigned long long mask0;

  const int tid  = threadIdx.x;
  const int lane = tid & 63;
  const int wv   = tid >> 6;
  const int b    = blockIdx.x;
  const float* bb = batch + (size_t)b * (NN * DN);
  const f16* hp = hpT + (size_t)b * HB;

  for (int i = tid; i < DF; i += 256) {
    asrcL[i] = a_src[i];
    adstL[i] = a_dst[i];
    biasL[i] = gat_bias[i];
  }
  if (wv == 0) {
    float av = bb[DF + lane];
    unsigned long long m = __ballot(av != 0.0f);
    if (lane == 0) mask0 = m | 1ULL;
  }
  __syncthreads();

  {
    float s = 0.f, d = 0.f;
    int o0 = wv * 192;
    for (int oi = 0; oi < 192; ++oi) {
      int o = o0 + oi;
      float t = tanh_fast((float)hp[(size_t)o * 64 + lane]);
      s += t * asrcL[o];
      d += t * adstL[o];
    }
    redS[wv * 64 + lane] = s;
    redD[wv * 64 + lane] = d;
  }
  __syncthreads();
  if (tid < 64) {
    dstv[tid] = redD[tid] + redD[64 + tid] + redD[128 + tid] + redD[192 + tid];
    if (tid == 0) srcv0 = redS[0] + redS[64] + redS[128] + redS[192];
  }
  __syncthreads();
  if (wv == 0) {
    float logit = srcv0 + dstv[lane];
    logit = logit >= 0.f ? logit : NEG_SLOPE * logit;
    bool ok = (mask0 >> lane) & 1ULL;
    float v = ok ? logit : -1e30f;
    float mx = v;
#pragma unroll
    for (int off = 32; off > 0; off >>= 1) mx = fmaxf(mx, __shfl_xor(mx, off, 64));
    float e = ok ? __expf(v - mx) : 0.f;
    float sm = e;
#pragma unroll
    for (int off = 32; off > 0; off >>= 1) sm += __shfl_xor(sm, off, 64);
    attn0[lane] = e / sm;
  }
  __syncthreads();
  for (int o = tid; o < DF; o += 256) {
    const f16* rp = hp + (size_t)o * 64;
    float a = biasL[o];
#pragma unroll
    for (int j = 0; j < 8; ++j) {
      f16x8 v = *(const f16x8*)&rp[j * 8];
#pragma unroll
      for (int e = 0; e < 8; ++e) a += attn0[j * 8 + e] * (float)v[e];
    }
    h2row[o] = a;
  }
  __syncthreads();
  float p = 0.f;
  for (int o = tid; o < DF; o += 256) p += h2row[o] * h2row[o];
#pragma unroll
  for (int off = 32; off > 0; off >>= 1) p += __shfl_xor(p, off, 64);
  if (lane == 0) ssq[wv] = p;
  __syncthreads();
  if (tid == 0) {
    float ss = ssq[0] + ssq[1] + ssq[2] + ssq[3];
    ssq[0] = 1.0f / fmaxf(sqrtf(ss), 1e-12f);
  }
  __syncthreads();
  float scale = ssq[0];
  for (int o = tid; o < DF; o += 256)
    cneighW[(size_t)b * DF + o] = (f16)(h2row[o] * scale);
}

// ---------- final MLP GEMM ----------
#define LDA 1540
__global__ __launch_bounds__(256) void final_mlp(
    const float* __restrict__ batch,
    const f16* __restrict__ cneighW,
    const f16* __restrict__ mwh,
    const float* __restrict__ mlp_b,
    float* __restrict__ out)
{
  __shared__ __align__(16) f16 Abuf[16 * LDA];
  const int tid  = threadIdx.x;
  const int lane = tid & 63;
  const int wv   = tid >> 6;
  const int l16  = lane & 15;
  const int quad = lane >> 4;
  const int b0   = blockIdx.x * 16;
  const int cb   = blockIdx.y * 128 + wv * 32;

  for (int i = tid; i < 16 * 384; i += 256) {
    int r = i / 384, c4 = i - r * 384;
    int j = c4 * 4;
    f16x4 h4;
    if (j < DF) {
      float4 v = *(const float4*)&batch[(size_t)(b0 + r) * (NN * DN) + j];
      h4 = (f16x4){(f16)v.x, (f16)v.y, (f16)v.z, (f16)v.w};
    } else {
      h4 = *(const f16x4*)&cneighW[(size_t)(b0 + r) * DF + (j - DF)];
    }
    *(f16x4*)&Abuf[r * LDA + j] = h4;
  }
  __syncthreads();

  f32x4 acc[2];
  acc[0] = (f32x4){0.f, 0.f, 0.f, 0.f};
  acc[1] = (f32x4){0.f, 0.f, 0.f, 0.f};

  const f16* mp = mwh + (size_t)(cb + l16) * (2 * DF) + quad * 8;
  f16x8 bfr[2], bnx[2];
  bfr[0] = *(const f16x8*)(mp);
  bfr[1] = *(const f16x8*)(mp + (size_t)16 * (2 * DF));

#pragma clang loop unroll(disable)
  for (int k0 = 0; k0 < 2 * DF; k0 += 32) {
    int kn = (k0 + 32 < 2 * DF) ? (k0 + 32) : 0;
    bnx[0] = *(const f16x8*)(mp + kn);
    bnx[1] = *(const f16x8*)(mp + (size_t)16 * (2 * DF) + kn);
    f16x4 a0 = *(const f16x4*)&Abuf[l16 * LDA + k0 + quad * 8];
    f16x4 a1 = *(const f16x4*)&Abuf[l16 * LDA + k0 + quad * 8 + 4];
    f16x8 af = {a0[0], a0[1], a0[2], a0[3], a1[0], a1[1], a1[2], a1[3]};
    acc[0] = __builtin_amdgcn_mfma_f32_16x16x32_f16(af, bfr[0], acc[0], 0, 0, 0);
    acc[1] = __builtin_amdgcn_mfma_f32_16x16x32_f16(af, bfr[1], acc[1], 0, 0, 0);
    bfr[0] = bnx[0];
    bfr[1] = bnx[1];
  }
#pragma unroll
  for (int ct = 0; ct < 2; ++ct) {
    int col = cb + ct * 16 + l16;
    float bv = mlp_b[col];
#pragma unroll
    for (int i = 0; i < 4; ++i) {
      int row = quad * 4 + i;
      out[(size_t)(b0 + row) * DF + col] = acc[ct][i] + bv;
    }
  }
}

__global__ __launch_bounds__(256) void l2norm_rows(float* __restrict__ out) {
  const int lane = threadIdx.x & 63;
  const int wv   = threadIdx.x >> 6;
  const int row  = blockIdx.x * 4 + wv;
  float* rp = out + (size_t)row * DF;
  float v[12];
  float ss = 0.f;
#pragma unroll
  for (int j = 0; j < 12; ++j) {
    v[j] = rp[j * 64 + lane];
    ss += v[j] * v[j];
  }
#pragma unroll
  for (int off = 32; off > 0; off >>= 1) ss += __shfl_xor(ss, off, 64);
  float sc = 1.0f / fmaxf(sqrtf(ss), 1e-12f);
#pragma unroll
  for (int j = 0; j < 12; ++j) rp[j * 64 + lane] = v[j] * sc;
}

extern "C" void kernel_launch(void* const* d_in, const int* in_sizes, int n_in,
                              void* d_out, int out_size, void* d_ws, size_t ws_size,
                              hipStream_t stream) {
  const float* batch    = (const float*)d_in[0];
  const float* w        = (const float*)d_in[1];
  const float* a_src    = (const float*)d_in[2];
  const float* a_dst    = (const float*)d_in[3];
  const float* gat_bias = (const float*)d_in[4];
  const float* mlp_w    = (const float*)d_in[5];
  const float* mlp_b    = (const float*)d_in[6];
  float* out = (float*)d_out;

  // workspace (f16): wT | mwh | cneigh | hA (hpT) | hB (h1)  ~= 105 MB
  f16* wT      = (f16*)d_ws;
  f16* mwh     = wT + (size_t)DF * DF;
  f16* cneighW = mwh + (size_t)DF * 2 * DF;
  f16* hA      = cneighW + (size_t)512 * DF;
  f16* hB      = hA + (size_t)512 * HB;

  prep_wT<<<dim3(24 * 24), dim3(256), 0, stream>>>(w, wT);
  prep_mlp<<<dim3((DF * 2 * DF) / 256), dim3(256), 0, stream>>>(mlp_w, mwh);
  // layer 1
  gemm_hp<<<dim3(1536), dim3(256), 0, stream>>>(batch, hB, wT, hA, 1);
  attn_l1<<<dim3(512), dim3(256), 0, stream>>>(batch, hA, a_src, a_dst, gat_bias, hB);
  // layer 2
  gemm_hp<<<dim3(1536), dim3(256), 0, stream>>>(batch, hB, wT, hA, 0);
  attn_l2<<<dim3(512), dim3(256), 0, stream>>>(batch, hA, a_src, a_dst, gat_bias, cneighW);
  // MLP + row l2norm
  final_mlp<<<dim3(32, 6), dim3(256), 0, stream>>>(batch, cneighW, mwh, mlp_b, out);
  l2norm_rows<<<dim3(128), dim3(256), 0, stream>>>(out);
}

// Round 8
// 403.667 us; speedup vs baseline: 1.1096x; 1.1096x over previous
//
#include <hip/hip_runtime.h>
#include <math.h>

#define DF 768      // feature dim
#define NN 64       // nodes
#define DN 832      // batch row stride (D + N)
#define HB 49152    // halves per batch item in h buffers (768*64)
#define NEG_SLOPE 0.2f

typedef _Float16 f16;
typedef __attribute__((ext_vector_type(4))) _Float16 f16x4;
typedef __attribute__((ext_vector_type(8))) _Float16 f16x8;
typedef __attribute__((ext_vector_type(4))) float f32x4;

__device__ __forceinline__ float tanh_fast(float x) {
  return 1.0f - 2.0f / (__expf(2.0f * x) + 1.0f);
}

// ---------- prep: transpose w (768x768 fp32) -> wT[o][k] f16 ----------
__global__ void prep_wT(const float* __restrict__ w, f16* __restrict__ wT) {
  __shared__ float tile[32][33];
  int bx = blockIdx.x % 24;
  int by = blockIdx.x / 24;
  int tx = threadIdx.x & 31;
  int ty = threadIdx.x >> 5;
#pragma unroll
  for (int rr = 0; rr < 4; ++rr)
    tile[ty + rr * 8][tx] = w[(size_t)(by * 32 + ty + rr * 8) * DF + bx * 32 + tx];
  __syncthreads();
#pragma unroll
  for (int rr = 0; rr < 4; ++rr)
    wT[(size_t)(bx * 32 + ty + rr * 8) * DF + by * 32 + tx] = (f16)tile[tx][ty + rr * 8];
}

// ---------- prep: mlp_w fp32 -> f16 ----------
__global__ void prep_mlp(const float* __restrict__ mw, f16* __restrict__ mwh) {
  int i = blockIdx.x * 256 + threadIdx.x;
  mwh[i] = (f16)mw[i];
}

// ---------- prep: batch features fp32 -> h0 f16 [32768][768] ----------
// R8: halves layer-1 GEMM A-traffic (201 MB fp32 -> 50 MB f16) and unifies
// the gemm A-path. One-time 158 MB pass (~25 us).
__global__ __launch_bounds__(256) void prep_h0(const float* __restrict__ batch,
                                               f16* __restrict__ h0) {
  int i = blockIdx.x * 256 + threadIdx.x;    // over 32768*192 float4 units
  int r = i / 192, c4 = (i - r * 192) * 4;
  float4 v = *(const float4*)&batch[(size_t)(r >> 6) * (NN * DN) + (size_t)(r & 63) * DN + c4];
  *(f16x4*)&h0[(size_t)r * DF + c4] = (f16x4){(f16)v.x, (f16)v.y, (f16)v.z, (f16)v.w};
}

// ---------- hp = h @ w : M=32768, N=768, K=768, double-buffered ----------
// R7 lesson: bn-fastest put the 6 blocks sharing an A-stripe on 6 DIFFERENT
// XCDs (round-robin blockIdx%8) -> 6x L2 replication, FETCH 302 MB, HBM-bound.
// R8: XCD-aware swizzle -- same-stripe blocks land on the SAME XCD, and
// consecutive slots walk bm sequentially for temporal L2 reuse.
__global__ __launch_bounds__(256, 2) void gemm_hp(
    const f16* __restrict__ hIn,     // [32768][768]
    const f16* __restrict__ wT,      // [768][768]
    f16* __restrict__ hpT)           // [b][o][m]
{
  __shared__ __align__(16) f16 At[2][128 * 72];
  __shared__ __align__(16) f16 Bt[2][128 * 72];
  const int tid  = threadIdx.x;
  const int lane = tid & 63;
  const int wv   = tid >> 6;
  const int l16  = lane & 15;
  const int quad = lane >> 4;
  const int j    = blockIdx.x;
  const int xcd  = j & 7;
  const int slot = j >> 3;           // 0..191
  const int bm   = xcd * 32 + slot / 6;
  const int bn   = slot % 6;
  const int m0w  = (wv & 1) * 64;
  const int n0w  = (wv >> 1) * 64;

  const int rH = tid >> 3, cH = (tid & 7) * 8;

  f32x4 acc[4][4];
#pragma unroll
  for (int rt = 0; rt < 4; ++rt)
#pragma unroll
    for (int ct = 0; ct < 4; ++ct)
      acc[rt][ct] = (f32x4){0.f, 0.f, 0.f, 0.f};

  f16x8 aR[4], bR[4];

#define PREF(KT_) do {                                                              \
    const int k0_ = (KT_) * 64;                                                     \
    _Pragma("unroll")                                                               \
    for (int p = 0; p < 4; ++p) {                                                   \
      aR[p] = *(const f16x8*)&hIn[(size_t)(bm * 128 + p * 32 + rH) * DF + k0_ + cH];\
      bR[p] = *(const f16x8*)&wT[(size_t)(bn * 128 + p * 32 + rH) * DF + k0_ + cH]; \
    }                                                                               \
  } while (0)

#define WRITE(BUF_) do {                                                            \
    _Pragma("unroll")                                                               \
    for (int p = 0; p < 4; ++p) {                                                   \
      *(f16x8*)&At[BUF_][(p * 32 + rH) * 72 + cH] = aR[p];                          \
      *(f16x8*)&Bt[BUF_][(p * 32 + rH) * 72 + cH] = bR[p];                          \
    }                                                                               \
  } while (0)

  PREF(0);
  WRITE(0);
  __syncthreads();

  for (int kt = 0; kt < 12; ++kt) {
    const int cur = kt & 1;
    if (kt < 11) PREF(kt + 1);
#pragma unroll
    for (int ks = 0; ks < 2; ++ks) {
      f16x8 af[4], bf[4];
#pragma unroll
      for (int rt = 0; rt < 4; ++rt)
        af[rt] = *(const f16x8*)&At[cur][(m0w + rt * 16 + l16) * 72 + ks * 32 + quad * 8];
#pragma unroll
      for (int ct = 0; ct < 4; ++ct)
        bf[ct] = *(const f16x8*)&Bt[cur][(n0w + ct * 16 + l16) * 72 + ks * 32 + quad * 8];
#pragma unroll
      for (int rt = 0; rt < 4; ++rt)
#pragma unroll
        for (int ct = 0; ct < 4; ++ct)
          acc[rt][ct] = __builtin_amdgcn_mfma_f32_16x16x32_f16(af[rt], bf[ct], acc[rt][ct], 0, 0, 0);
    }
    if (kt < 11) {
      WRITE(cur ^ 1);
      __syncthreads();
    }
  }
#undef PREF
#undef WRITE

  // epilogue: hpT[b][o][m], 4 consecutive m per frag -> f16x4 store
#pragma unroll
  for (int rt = 0; rt < 4; ++rt)
#pragma unroll
    for (int ct = 0; ct < 4; ++ct) {
      int gm = bm * 128 + m0w + rt * 16 + quad * 4;
      int b = gm >> 6, mm = gm & 63;
      int o = bn * 128 + n0w + ct * 16 + l16;
      f16x4 hv = {(f16)acc[rt][ct][0], (f16)acc[rt][ct][1],
                  (f16)acc[rt][ct][2], (f16)acc[rt][ct][3]};
      *(f16x4*)&hpT[(size_t)b * HB + (size_t)o * 64 + mm] = hv;
    }
}

// ---------- attention layer 1: tanh-dots + masked softmax + h1 = attn@hp + bias ----------
__global__ __launch_bounds__(256) void attn_l1(
    const float* __restrict__ batch,
    const f16* __restrict__ hpT,      // [b][o][m]
    const float* __restrict__ a_src,
    const float* __restrict__ a_dst,
    const float* __restrict__ gat_bias,
    f16* __restrict__ h1)             // [b][m][o]
{
  __shared__ __align__(16) f16 attnL[NN * 72];
  __shared__ float asrcL[DF], adstL[DF], biasL[DF];
  __shared__ float redS[4 * NN], redD[4 * NN];
  __shared__ float srcv[NN], dstv[NN];
  __shared__ unsigned long long maskRow[NN];

  const int tid  = threadIdx.x;
  const int lane = tid & 63;
  const int wv   = tid >> 6;    // 0..3
  const int l16  = lane & 15;
  const int quad = lane >> 4;
  const int b    = blockIdx.x;
  const float* bb = batch + (size_t)b * (NN * DN);
  const f16* hp = hpT + (size_t)b * HB;

  for (int i = tid; i < DF; i += 256) {
    asrcL[i] = a_src[i];
    adstL[i] = a_dst[i];
    biasL[i] = gat_bias[i];
  }
#pragma unroll
  for (int r = 0; r < 16; ++r) {
    int n = wv * 16 + r;
    float av = bb[n * DN + DF + lane];
    unsigned long long m = __ballot(av != 0.0f);
    if (lane == 0) maskRow[n] = m | (1ULL << n);
  }
  __syncthreads();

  // tanh dots: wave wv covers o in [192wv, +192), lane = m
  {
    float s = 0.f, d = 0.f;
    int o0 = wv * 192;
    for (int oi = 0; oi < 192; ++oi) {
      int o = o0 + oi;
      float t = tanh_fast((float)hp[(size_t)o * 64 + lane]);
      s += t * asrcL[o];
      d += t * adstL[o];
    }
    redS[wv * 64 + lane] = s;
    redD[wv * 64 + lane] = d;
  }
  __syncthreads();
  if (tid < 64) {
    srcv[tid] = redS[tid] + redS[64 + tid] + redS[128 + tid] + redS[192 + tid];
    dstv[tid] = redD[tid] + redD[64 + tid] + redD[128 + tid] + redD[192 + tid];
  }
  __syncthreads();

  // softmax: wave wv rows 16wv..+15, lane = neighbor m
#pragma unroll
  for (int r = 0; r < 16; ++r) {
    int n = wv * 16 + r;
    float logit = srcv[n] + dstv[lane];
    logit = logit >= 0.f ? logit : NEG_SLOPE * logit;
    bool ok = (maskRow[n] >> lane) & 1ULL;
    float v = ok ? logit : -1e30f;
    float mx = v;
#pragma unroll
    for (int off = 32; off > 0; off >>= 1) mx = fmaxf(mx, __shfl_xor(mx, off, 64));
    float e = ok ? __expf(v - mx) : 0.f;
    float sm = e;
#pragma unroll
    for (int off = 32; off > 0; off >>= 1) sm += __shfl_xor(sm, off, 64);
    attnL[n * 72 + lane] = (f16)(e / sm);
  }
  __syncthreads();

  // GEMM2: wave wv outputs cols o in [192wv, +192) as 12 tiles of 16;
  // B-fragments prefetched one ct ahead (global, L2-hot).
  f16x8 b0 = *(const f16x8*)&hp[(size_t)(wv * 192 + l16) * 64 + quad * 8];
  f16x8 b1 = *(const f16x8*)&hp[(size_t)(wv * 192 + l16) * 64 + 32 + quad * 8];
  for (int ct = 0; ct < 12; ++ct) {
    int c0 = wv * 192 + ct * 16;
    f16x8 n0, n1;
    if (ct < 11) {
      n0 = *(const f16x8*)&hp[(size_t)(c0 + 16 + l16) * 64 + quad * 8];
      n1 = *(const f16x8*)&hp[(size_t)(c0 + 16 + l16) * 64 + 32 + quad * 8];
    }
    f32x4 a4[4];
#pragma unroll
    for (int rt = 0; rt < 4; ++rt) a4[rt] = (f32x4){0.f, 0.f, 0.f, 0.f};
#pragma unroll
    for (int rt = 0; rt < 4; ++rt) {
      f16x8 af = *(const f16x8*)&attnL[(rt * 16 + l16) * 72 + quad * 8];
      a4[rt] = __builtin_amdgcn_mfma_f32_16x16x32_f16(af, b0, a4[rt], 0, 0, 0);
    }
#pragma unroll
    for (int rt = 0; rt < 4; ++rt) {
      f16x8 af = *(const f16x8*)&attnL[(rt * 16 + l16) * 72 + 32 + quad * 8];
      a4[rt] = __builtin_amdgcn_mfma_f32_16x16x32_f16(af, b1, a4[rt], 0, 0, 0);
    }
    float bv = biasL[c0 + l16];
#pragma unroll
    for (int rt = 0; rt < 4; ++rt)
#pragma unroll
      for (int i = 0; i < 4; ++i) {
        int n = rt * 16 + quad * 4 + i;
        h1[(size_t)b * HB + (size_t)n * DF + c0 + l16] = (f16)(a4[rt][i] + bv);
      }
    b0 = n0;
    b1 = n1;
  }
}

// ---------- attention layer 2: only row 0 -> cneigh (l2-normed) ----------
__global__ __launch_bounds__(256) void attn_l2(
    const float* __restrict__ batch,
    const f16* __restrict__ hpT,
    const float* __restrict__ a_src,
    const float* __restrict__ a_dst,
    const float* __restrict__ gat_bias,
    f16* __restrict__ cneighW)
{
  __shared__ float asrcL[DF], adstL[DF], biasL[DF];
  __shared__ float redS[4 * NN], redD[4 * NN];
  __shared__ float dstv[NN], attn0[NN], h2row[DF], ssq[4];
  __shared__ float srcv0;
  __shared__ unsigned long long mask0;

  const int tid  = threadIdx.x;
  const int lane = tid & 63;
  const int wv   = tid >> 6;
  const int b    = blockIdx.x;
  const float* bb = batch + (size_t)b * (NN * DN);
  const f16* hp = hpT + (size_t)b * HB;

  for (int i = tid; i < DF; i += 256) {
    asrcL[i] = a_src[i];
    adstL[i] = a_dst[i];
    biasL[i] = gat_bias[i];
  }
  if (wv == 0) {
    float av = bb[DF + lane];
    unsigned long long m = __ballot(av != 0.0f);
    if (lane == 0) mask0 = m | 1ULL;
  }
  __syncthreads();

  {
    float s = 0.f, d = 0.f;
    int o0 = wv * 192;
    for (int oi = 0; oi < 192; ++oi) {
      int o = o0 + oi;
      float t = tanh_fast((float)hp[(size_t)o * 64 + lane]);
      s += t * asrcL[o];
      d += t * adstL[o];
    }
    redS[wv * 64 + lane] = s;
    redD[wv * 64 + lane] = d;
  }
  __syncthreads();
  if (tid < 64) {
    dstv[tid] = redD[tid] + redD[64 + tid] + redD[128 + tid] + redD[192 + tid];
    if (tid == 0) srcv0 = redS[0] + redS[64] + redS[128] + redS[192];
  }
  __syncthreads();
  if (wv == 0) {
    float logit = srcv0 + dstv[lane];
    logit = logit >= 0.f ? logit : NEG_SLOPE * logit;
    bool ok = (mask0 >> lane) & 1ULL;
    float v = ok ? logit : -1e30f;
    float mx = v;
#pragma unroll
    for (int off = 32; off > 0; off >>= 1) mx = fmaxf(mx, __shfl_xor(mx, off, 64));
    float e = ok ? __expf(v - mx) : 0.f;
    float sm = e;
#pragma unroll
    for (int off = 32; off > 0; off >>= 1) sm += __shfl_xor(sm, off, 64);
    attn0[lane] = e / sm;
  }
  __syncthreads();
  for (int o = tid; o < DF; o += 256) {
    const f16* rp = hp + (size_t)o * 64;
    float a = biasL[o];
#pragma unroll
    for (int j = 0; j < 8; ++j) {
      f16x8 v = *(const f16x8*)&rp[j * 8];
#pragma unroll
      for (int e = 0; e < 8; ++e) a += attn0[j * 8 + e] * (float)v[e];
    }
    h2row[o] = a;
  }
  __syncthreads();
  float p = 0.f;
  for (int o = tid; o < DF; o += 256) p += h2row[o] * h2row[o];
#pragma unroll
  for (int off = 32; off > 0; off >>= 1) p += __shfl_xor(p, off, 64);
  if (lane == 0) ssq[wv] = p;
  __syncthreads();
  if (tid == 0) {
    float ss = ssq[0] + ssq[1] + ssq[2] + ssq[3];
    ssq[0] = 1.0f / fmaxf(sqrtf(ss), 1e-12f);
  }
  __syncthreads();
  float scale = ssq[0];
  for (int o = tid; o < DF; o += 256)
    cneighW[(size_t)b * DF + o] = (f16)(h2row[o] * scale);
}

// ---------- final MLP GEMM ----------
#define LDA 1540
__global__ __launch_bounds__(256) void final_mlp(
    const float* __restrict__ batch,
    const f16* __restrict__ cneighW,
    const f16* __restrict__ mwh,
    const float* __restrict__ mlp_b,
    float* __restrict__ out)
{
  __shared__ __align__(16) f16 Abuf[16 * LDA];
  const int tid  = threadIdx.x;
  const int lane = tid & 63;
  const int wv   = tid >> 6;
  const int l16  = lane & 15;
  const int quad = lane >> 4;
  const int b0   = blockIdx.x * 16;
  const int cb   = blockIdx.y * 128 + wv * 32;

  for (int i = tid; i < 16 * 384; i += 256) {
    int r = i / 384, c4 = i - r * 384;
    int j = c4 * 4;
    f16x4 h4;
    if (j < DF) {
      float4 v = *(const float4*)&batch[(size_t)(b0 + r) * (NN * DN) + j];
      h4 = (f16x4){(f16)v.x, (f16)v.y, (f16)v.z, (f16)v.w};
    } else {
      h4 = *(const f16x4*)&cneighW[(size_t)(b0 + r) * DF + (j - DF)];
    }
    *(f16x4*)&Abuf[r * LDA + j] = h4;
  }
  __syncthreads();

  f32x4 acc[2];
  acc[0] = (f32x4){0.f, 0.f, 0.f, 0.f};
  acc[1] = (f32x4){0.f, 0.f, 0.f, 0.f};

  const f16* mp = mwh + (size_t)(cb + l16) * (2 * DF) + quad * 8;
  f16x8 bfr[2], bnx[2];
  bfr[0] = *(const f16x8*)(mp);
  bfr[1] = *(const f16x8*)(mp + (size_t)16 * (2 * DF));

#pragma clang loop unroll(disable)
  for (int k0 = 0; k0 < 2 * DF; k0 += 32) {
    int kn = (k0 + 32 < 2 * DF) ? (k0 + 32) : 0;
    bnx[0] = *(const f16x8*)(mp + kn);
    bnx[1] = *(const f16x8*)(mp + (size_t)16 * (2 * DF) + kn);
    f16x4 a0 = *(const f16x4*)&Abuf[l16 * LDA + k0 + quad * 8];
    f16x4 a1 = *(const f16x4*)&Abuf[l16 * LDA + k0 + quad * 8 + 4];
    f16x8 af = {a0[0], a0[1], a0[2], a0[3], a1[0], a1[1], a1[2], a1[3]};
    acc[0] = __builtin_amdgcn_mfma_f32_16x16x32_f16(af, bfr[0], acc[0], 0, 0, 0);
    acc[1] = __builtin_amdgcn_mfma_f32_16x16x32_f16(af, bfr[1], acc[1], 0, 0, 0);
    bfr[0] = bnx[0];
    bfr[1] = bnx[1];
  }
#pragma unroll
  for (int ct = 0; ct < 2; ++ct) {
    int col = cb + ct * 16 + l16;
    float bv = mlp_b[col];
#pragma unroll
    for (int i = 0; i < 4; ++i) {
      int row = quad * 4 + i;
      out[(size_t)(b0 + row) * DF + col] = acc[ct][i] + bv;
    }
  }
}

__global__ __launch_bounds__(256) void l2norm_rows(float* __restrict__ out) {
  const int lane = threadIdx.x & 63;
  const int wv   = threadIdx.x >> 6;
  const int row  = blockIdx.x * 4 + wv;
  float* rp = out + (size_t)row * DF;
  float v[12];
  float ss = 0.f;
#pragma unroll
  for (int j = 0; j < 12; ++j) {
    v[j] = rp[j * 64 + lane];
    ss += v[j] * v[j];
  }
#pragma unroll
  for (int off = 32; off > 0; off >>= 1) ss += __shfl_xor(ss, off, 64);
  float sc = 1.0f / fmaxf(sqrtf(ss), 1e-12f);
#pragma unroll
  for (int j = 0; j < 12; ++j) rp[j * 64 + lane] = v[j] * sc;
}

extern "C" void kernel_launch(void* const* d_in, const int* in_sizes, int n_in,
                              void* d_out, int out_size, void* d_ws, size_t ws_size,
                              hipStream_t stream) {
  const float* batch    = (const float*)d_in[0];
  const float* w        = (const float*)d_in[1];
  const float* a_src    = (const float*)d_in[2];
  const float* a_dst    = (const float*)d_in[3];
  const float* gat_bias = (const float*)d_in[4];
  const float* mlp_w    = (const float*)d_in[5];
  const float* mlp_b    = (const float*)d_in[6];
  float* out = (float*)d_out;

  // workspace (f16): wT | mwh | cneigh | hA | hB  ~= 105 MB
  // hB lifetime: h0 (prep_h0 -> gemm1) then h1 (attn_l1 -> gemm2)
  f16* wT      = (f16*)d_ws;
  f16* mwh     = wT + (size_t)DF * DF;
  f16* cneighW = mwh + (size_t)DF * 2 * DF;
  f16* hA      = cneighW + (size_t)512 * DF;
  f16* hB      = hA + (size_t)512 * HB;

  prep_wT<<<dim3(24 * 24), dim3(256), 0, stream>>>(w, wT);
  prep_mlp<<<dim3((DF * 2 * DF) / 256), dim3(256), 0, stream>>>(mlp_w, mwh);
  prep_h0<<<dim3(24576), dim3(256), 0, stream>>>(batch, hB);
  // layer 1
  gemm_hp<<<dim3(1536), dim3(256), 0, stream>>>(hB, wT, hA);
  attn_l1<<<dim3(512), dim3(256), 0, stream>>>(batch, hA, a_src, a_dst, gat_bias, hB);
  // layer 2
  gemm_hp<<<dim3(1536), dim3(256), 0, stream>>>(hB, wT, hA);
  attn_l2<<<dim3(512), dim3(256), 0, stream>>>(batch, hA, a_src, a_dst, gat_bias, cneighW);
  // MLP + row l2norm
  final_mlp<<<dim3(32, 6), dim3(256), 0, stream>>>(batch, cneighW, mwh, mlp_b, out);
  l2norm_rows<<<dim3(128), dim3(256), 0, stream>>>(out);
}